// Round 3
// baseline (679.198 us; speedup 1.0000x reference)
//
#include <hip/hip_runtime.h>

// BranchNet fused pipeline (2 kernels):
//   k_prep: Wcomb = Wb@We.T (fp64), bcomb; Wfold[b] = Wb@Wc[b] (bf16 [b][c][k]); bfold.
//   k_main: per 32-row block: stage x fp32->LDS (single x read) -> fp64 routing
//           (Wcomb in VGPRs, x broadcast from LDS) -> MFMA logits for ALL 8 branches
//           -> predicated stores of the argmin branch's 128 cols.
// 32-row blocks keep LDS at 33.4 KB -> 4 blocks/CU (16 waves/CU) vs round-1's 2.
// Sizes: N=131072, IN=256, HID=256, B=8, C=128.

#define NROWS 131072
#define ROWS  32
#define XST   260   // xs row stride in floats; 260/4=65 odd -> bank-quad (r+2q)%8 uniform

typedef __bf16 bf16x8 __attribute__((ext_vector_type(8)));
typedef float  f32x4  __attribute__((ext_vector_type(4)));
typedef unsigned short u16x8 __attribute__((ext_vector_type(8)));

__device__ __forceinline__ unsigned short f2bf(float f) {
    unsigned u = __builtin_bit_cast(unsigned, f);
    u += 0x7fffu + ((u >> 16) & 1u);   // RNE
    return (unsigned short)(u >> 16);
}

// ---------- prep: blocks 0..7 comb(b), 8..15 bfold(b), 16..143 fold ----------
__global__ __launch_bounds__(256) void k_prep(const float* __restrict__ Wb,
                                              const float* __restrict__ bb,
                                              const float* __restrict__ Wc,
                                              const float* __restrict__ bc,
                                              const float* __restrict__ We,
                                              const float* __restrict__ be,
                                              double* __restrict__ Wcomb,
                                              double* __restrict__ bcomb,
                                              unsigned short* __restrict__ Wfold,
                                              float* __restrict__ bfold) {
    __shared__ float clf[32][128];
    __shared__ float wbt[32][16];
    __shared__ double red[256];
    __shared__ float part[256];
    int blk = blockIdx.x, tid = threadIdx.x;

    if (blk < 8) {
        // Wcomb[b][k] = sum_h Wb[k][h] * We[b][h]  (fp64), bcomb[b]
        int b = blk, k = tid;
        const float4* wbr = (const float4*)(Wb + k * 256);
        const float4* wer = (const float4*)(We + b * 256);
        double a0 = 0.0, a1 = 0.0, a2 = 0.0, a3 = 0.0;
#pragma unroll 8
        for (int j = 0; j < 64; ++j) {
            float4 u = wbr[j], w = wer[j];
            a0 += (double)u.x * (double)w.x;
            a1 += (double)u.y * (double)w.y;
            a2 += (double)u.z * (double)w.z;
            a3 += (double)u.w * (double)w.w;
        }
        Wcomb[b * 256 + k] = (a0 + a1) + (a2 + a3);

        red[k] = (double)bb[k] * (double)We[b * 256 + k];
        __syncthreads();
        for (int s = 128; s; s >>= 1) {
            if (k < s) red[k] += red[k + s];
            __syncthreads();
        }
        if (k == 0) bcomb[b] = red[0] + (double)be[b];
        return;
    }

    if (blk < 16) {
        // b_fold[b][c] = bc[b][c] + sum_h bb[h]*Wc[b][h][c]; one branch/block, 2-way h split
        int b = blk - 8;
        int c = tid & 127, hg = tid >> 7;
        float a = 0.f;
#pragma unroll 16
        for (int h = 0; h < 128; ++h)
            a += bb[hg * 128 + h] * Wc[((b * 256 + hg * 128 + h)) * 128 + c];
        part[tid] = a;
        __syncthreads();
        if (tid < 128) bfold[b * 128 + tid] = part[tid] + part[tid + 128] + bc[b * 128 + tid];
        return;
    }

    // fold: Wfold[b][c][k] bf16  (= sum_h Wb[k][h]*Wc[b][h][c])
    int idx0 = blk - 16;
    int kg = idx0 & 15, b = idx0 >> 4;
    int c = tid & 127, kh = tid >> 7;

    float acc[8];
#pragma unroll
    for (int j = 0; j < 8; ++j) acc[j] = 0.f;

    for (int ht = 0; ht < 8; ++ht) {
#pragma unroll
        for (int j = 0; j < 16; ++j) {
            int idx = tid + j * 256;
            int hh = idx >> 7, cc = idx & 127;
            clf[hh][cc] = Wc[(b * 256 + ht * 32 + hh) * 128 + cc];
        }
#pragma unroll
        for (int j = 0; j < 2; ++j) {
            int idx = tid + j * 256;
            int hh = idx & 31, kk = idx >> 5;
            wbt[hh][kk] = Wb[(kg * 16 + kk) * 256 + ht * 32 + hh];
        }
        __syncthreads();
        for (int h = 0; h < 32; ++h) {
            float wc = clf[h][c];
            float4 w0 = *(const float4*)&wbt[h][kh * 8];
            float4 w1 = *(const float4*)&wbt[h][kh * 8 + 4];
            acc[0] += w0.x * wc; acc[1] += w0.y * wc;
            acc[2] += w0.z * wc; acc[3] += w0.w * wc;
            acc[4] += w1.x * wc; acc[5] += w1.y * wc;
            acc[6] += w1.z * wc; acc[7] += w1.w * wc;
        }
        __syncthreads();
    }
    unsigned short o8[8];
#pragma unroll
    for (int j = 0; j < 8; ++j) o8[j] = f2bf(acc[j]);
    u16x8 pk;
#pragma unroll
    for (int j = 0; j < 8; ++j) pk[j] = o8[j];
    int base = (b * 128 + c) * 256 + kg * 16 + kh * 8;
    *(u16x8*)&Wfold[base] = pk;
}

// ---------- fused: stage -> route (fp64) -> all-branch MFMA -> predicated store ----------
__global__ __launch_bounds__(256, 4) void k_main(const float* __restrict__ x,
                                                 const double* __restrict__ Wcomb,
                                                 const double* __restrict__ bcomb,
                                                 const unsigned short* __restrict__ Wfold,
                                                 const float* __restrict__ bfold,
                                                 float* __restrict__ out) {
    __shared__ float xs[ROWS * XST];   // 33280 B fp32 row cache
    __shared__ int bids[ROWS];

    const int tid = threadIdx.x;
    const int wave = tid >> 6, lane = tid & 63;
    const int bl = lane & 7, kc = lane >> 3;   // routing layout: lane = kc*8 + bl
    const size_t rowbase = (size_t)blockIdx.x * ROWS;

    // Wcomb into VGPRs: w?[t] = Wcomb[bl][kc*4 + t*32 + {0,1,2,3}]  (round-1 layout/order)
    double w0[8], w1[8], w2[8], w3[8];
    {
        const double* wb = Wcomb + bl * 256 + kc * 4;
#pragma unroll
        for (int t = 0; t < 8; ++t) {
            double2 p0 = *(const double2*)(wb + t * 32);
            double2 p1 = *(const double2*)(wb + t * 32 + 2);
            w0[t] = p0.x; w1[t] = p0.y; w2[t] = p1.x; w3[t] = p1.y;
        }
    }
    const double bco = bcomb[bl];

    // ---- phase A: stage 32 fp32 rows -> LDS (coalesced 1KB per wave-instr)
#pragma unroll
    for (int it = 0; it < 8; ++it) {
        int idx = it * 256 + tid;
        int r = idx >> 6, gq = idx & 63;
        float4 v = *(const float4*)(x + (rowbase + r) * 256 + gq * 4);
        *(float4*)&xs[r * XST + gq * 4] = v;
    }
    __syncthreads();

    // ---- phase B: route 8 rows per wave; fp64; x broadcast from LDS, W in VGPRs
    for (int rr = 0; rr < 8; ++rr) {
        int r = wave * 8 + rr;
        const float* xr = xs + r * XST + kc * 4;
        double a0 = 0.0, a1 = 0.0, a2 = 0.0, a3 = 0.0;
#pragma unroll
        for (int t = 0; t < 8; ++t) {
            float4 v = *(const float4*)(xr + t * 32);
            a0 += (double)v.x * w0[t];
            a1 += (double)v.y * w1[t];
            a2 += (double)v.z * w2[t];
            a3 += (double)v.w * w3[t];
        }
        double e = (a0 + a2) + (a1 + a3);
        e += __shfl_xor(e, 8);     // reduce over kc
        e += __shfl_xor(e, 16);
        e += __shfl_xor(e, 32);
        e += bco;
        int bid = bl;
#pragma unroll
        for (int d = 4; d; d >>= 1) {   // argmin over bl, first-index tie-break
            double o = __shfl_xor(e, d);
            int ob = __shfl_xor(bid, d);
            if (o < e || (o == e && ob < bid)) { e = o; bid = ob; }
        }
        if (lane == 0) bids[r] = bid;
    }
    __syncthreads();

    // ---- phase D: all-branch MFMA. wave -> (row-group rg, col-half chalf).
    // Af built ONCE per wave; Bf streams from L2-resident Wfold; stores predicated on bid.
    const int rg = wave & 1, chalf = wave >> 1;
    const int n16 = lane & 15, quad = lane >> 4;

    const float* ap = xs + (rg * 16 + n16) * XST + quad * 8;
    bf16x8 Af[8];
#pragma unroll
    for (int kt = 0; kt < 8; ++kt) {
        float4 f0 = *(const float4*)(ap + kt * 32);
        float4 f1 = *(const float4*)(ap + kt * 32 + 4);
        u16x8 pk;
        pk[0] = f2bf(f0.x); pk[1] = f2bf(f0.y); pk[2] = f2bf(f0.z); pk[3] = f2bf(f0.w);
        pk[4] = f2bf(f1.x); pk[5] = f2bf(f1.y); pk[6] = f2bf(f1.z); pk[7] = f2bf(f1.w);
        Af[kt] = __builtin_bit_cast(bf16x8, pk);
    }

    int mybid[4];
#pragma unroll
    for (int reg = 0; reg < 4; ++reg)
        mybid[reg] = bids[rg * 16 + quad * 4 + reg];

    for (int b = 0; b < 8; ++b) {
#pragma unroll 2
        for (int c4 = 0; c4 < 4; ++c4) {
            int ct = chalf * 4 + c4;
            const unsigned short* wp =
                Wfold + (size_t)(b * 128 + ct * 16 + n16) * 256 + quad * 8;
            bf16x8 Bf[8];
#pragma unroll
            for (int kt = 0; kt < 8; ++kt)
                Bf[kt] = __builtin_bit_cast(bf16x8, *(const u16x8*)(wp + kt * 32));
            float bias = bfold[b * 128 + ct * 16 + n16];
            f32x4 acc = {bias, bias, bias, bias};
#pragma unroll
            for (int kt = 0; kt < 8; ++kt)
                acc = __builtin_amdgcn_mfma_f32_16x16x32_bf16(Af[kt], Bf[kt], acc, 0, 0, 0);
#pragma unroll
            for (int reg = 0; reg < 4; ++reg)
                if (mybid[reg] == b)
                    out[(rowbase + rg * 16 + quad * 4 + reg) * 128 + ct * 16 + n16] = acc[reg];
        }
    }
}

extern "C" void kernel_launch(void* const* d_in, const int* in_sizes, int n_in,
                              void* d_out, int out_size, void* d_ws, size_t ws_size,
                              hipStream_t stream) {
    const float* x  = (const float*)d_in[0];
    const float* Wb = (const float*)d_in[1];
    const float* bb = (const float*)d_in[2];
    const float* Wc = (const float*)d_in[3];
    const float* bc = (const float*)d_in[4];
    const float* We = (const float*)d_in[5];
    const float* be = (const float*)d_in[6];
    float* out = (float*)d_out;

    unsigned char* ws = (unsigned char*)d_ws;
    double* Wcomb = (double*)ws;                               //       0 : 16384 B
    double* bcomb = (double*)(ws + 16384);                     //   16384 : 64 B
    unsigned short* Wfold = (unsigned short*)(ws + 16448);     //   16448 : 524288 B
    float* bfold = (float*)(ws + 540736);                      //  540736 : 4096 B -> 544832 total

    hipLaunchKernelGGL(k_prep, dim3(144), dim3(256), 0, stream,
                       Wb, bb, Wc, bc, We, be, Wcomb, bcomb, Wfold, bfold);
    hipLaunchKernelGGL(k_main, dim3(NROWS / ROWS), dim3(256), 0, stream,
                       x, Wcomb, bcomb, Wfold, bfold, out);
}

// Round 4
// 380.274 us; speedup vs baseline: 1.7861x; 1.7861x over previous
//
#include <hip/hip_runtime.h>

// BranchNet pipeline, de-fused (3 kernels):
//   k_prep : Wcomb = Wb@We.T (fp64), bcomb; Wfold[b]=Wb@Wc[b] (bf16 [b][c][k]); bfold.
//   k_route: fp64 routing, Wcomb in VGPRs (no LDS), wave-per-row 8bx8kc layout;
//            block-level compaction into per-branch fixed regions perm[b*N + ofs].
//   k_gemm : per (branch, 64-row tile): gather rows -> bf16 LDS -> 16x16x32 MFMA.
// Round-3 lesson: routing+MFMA in one kernel spills the 32 fp64 Wcomb regs (VGPR=56
// observed, scratch in hot loop, 528us). Keep phases in separate kernels.
// Sizes: N=131072, IN=256, HID=256, B=8, C=128.

#define NROWS 131072

typedef __bf16 bf16x8 __attribute__((ext_vector_type(8)));
typedef float  f32x4  __attribute__((ext_vector_type(4)));
typedef unsigned short u16x8 __attribute__((ext_vector_type(8)));

__device__ __forceinline__ unsigned short f2bf(float f) {
    unsigned u = __builtin_bit_cast(unsigned, f);
    u += 0x7fffu + ((u >> 16) & 1u);   // RNE
    return (unsigned short)(u >> 16);
}

// ---------- prep: blocks 0..7 comb(b) [+zero gcnt], 8..15 bfold(b), 16..143 fold ----------
__global__ __launch_bounds__(256) void k_prep(const float* __restrict__ Wb,
                                              const float* __restrict__ bb,
                                              const float* __restrict__ Wc,
                                              const float* __restrict__ bc,
                                              const float* __restrict__ We,
                                              const float* __restrict__ be,
                                              double* __restrict__ Wcomb,
                                              double* __restrict__ bcomb,
                                              unsigned short* __restrict__ Wfold,
                                              float* __restrict__ bfold,
                                              int* __restrict__ gcnt) {
    __shared__ float clf[32][128];
    __shared__ float wbt[32][16];
    __shared__ double red[256];
    __shared__ float part[256];
    int blk = blockIdx.x, tid = threadIdx.x;

    if (blk < 8) {
        if (blk == 0 && tid < 16) gcnt[tid] = 0;
        // Wcomb[b][k] = sum_h Wb[k][h] * We[b][h]  (fp64), bcomb[b]
        int b = blk, k = tid;
        const float4* wbr = (const float4*)(Wb + k * 256);
        const float4* wer = (const float4*)(We + b * 256);
        double a0 = 0.0, a1 = 0.0, a2 = 0.0, a3 = 0.0;
#pragma unroll 8
        for (int j = 0; j < 64; ++j) {
            float4 u = wbr[j], w = wer[j];
            a0 += (double)u.x * (double)w.x;
            a1 += (double)u.y * (double)w.y;
            a2 += (double)u.z * (double)w.z;
            a3 += (double)u.w * (double)w.w;
        }
        Wcomb[b * 256 + k] = (a0 + a1) + (a2 + a3);

        red[k] = (double)bb[k] * (double)We[b * 256 + k];
        __syncthreads();
        for (int s = 128; s; s >>= 1) {
            if (k < s) red[k] += red[k + s];
            __syncthreads();
        }
        if (k == 0) bcomb[b] = red[0] + (double)be[b];
        return;
    }

    if (blk < 16) {
        // b_fold[b][c] = bc[b][c] + sum_h bb[h]*Wc[b][h][c]; one branch/block, 2-way h split
        int b = blk - 8;
        int c = tid & 127, hg = tid >> 7;
        float a = 0.f;
#pragma unroll 16
        for (int h = 0; h < 128; ++h)
            a += bb[hg * 128 + h] * Wc[((b * 256 + hg * 128 + h)) * 128 + c];
        part[tid] = a;
        __syncthreads();
        if (tid < 128) bfold[b * 128 + tid] = part[tid] + part[tid + 128] + bc[b * 128 + tid];
        return;
    }

    // fold: Wfold[b][c][k] bf16  (= sum_h Wb[k][h]*Wc[b][h][c])
    int idx0 = blk - 16;
    int kg = idx0 & 15, b = idx0 >> 4;
    int c = tid & 127, kh = tid >> 7;

    float acc[8];
#pragma unroll
    for (int j = 0; j < 8; ++j) acc[j] = 0.f;

    for (int ht = 0; ht < 8; ++ht) {
#pragma unroll
        for (int j = 0; j < 16; ++j) {
            int idx = tid + j * 256;
            int hh = idx >> 7, cc = idx & 127;
            clf[hh][cc] = Wc[(b * 256 + ht * 32 + hh) * 128 + cc];
        }
#pragma unroll
        for (int j = 0; j < 2; ++j) {
            int idx = tid + j * 256;
            int hh = idx & 31, kk = idx >> 5;
            wbt[hh][kk] = Wb[(kg * 16 + kk) * 256 + ht * 32 + hh];
        }
        __syncthreads();
        for (int h = 0; h < 32; ++h) {
            float wc = clf[h][c];
            float4 w0 = *(const float4*)&wbt[h][kh * 8];
            float4 w1 = *(const float4*)&wbt[h][kh * 8 + 4];
            acc[0] += w0.x * wc; acc[1] += w0.y * wc;
            acc[2] += w0.z * wc; acc[3] += w0.w * wc;
            acc[4] += w1.x * wc; acc[5] += w1.y * wc;
            acc[6] += w1.z * wc; acc[7] += w1.w * wc;
        }
        __syncthreads();
    }
    unsigned short o8[8];
#pragma unroll
    for (int j = 0; j < 8; ++j) o8[j] = f2bf(acc[j]);
    u16x8 pk;
#pragma unroll
    for (int j = 0; j < 8; ++j) pk[j] = o8[j];
    int base = (b * 128 + c) * 256 + kg * 16 + kh * 8;
    *(u16x8*)&Wfold[base] = pk;
}

// ---------- route: fp64, W in VGPRs, x from global (broadcast loads); fused compaction ----------
// 64 rows/block; wave-per-row layout lane = kc*8 + bl (verified rounds 1/3).
__global__ __launch_bounds__(256) void k_route(const float* __restrict__ x,
                                               const double* __restrict__ Wcomb,
                                               const double* __restrict__ bcomb,
                                               int* __restrict__ gcnt,
                                               int* __restrict__ perm) {
    __shared__ unsigned char bidl[64];
    __shared__ unsigned char list[8][64];
    __shared__ int cnt[8], base8[8];

    const int tid = threadIdx.x;
    const int wave = tid >> 6, lane = tid & 63;
    const int bl = lane & 7, kc = lane >> 3;
    const size_t rowbase = (size_t)blockIdx.x * 64;

    if (tid < 8) cnt[tid] = 0;

    // Wcomb into VGPRs: w?[t] = Wcomb[bl][kc*4 + t*32 + {0,1,2,3}]
    double w0[8], w1[8], w2[8], w3[8];
    {
        const double* wb = Wcomb + bl * 256 + kc * 4;
#pragma unroll
        for (int t = 0; t < 8; ++t) {
            double2 p0 = *(const double2*)(wb + t * 32);
            double2 p1 = *(const double2*)(wb + t * 32 + 2);
            w0[t] = p0.x; w1[t] = p0.y; w2[t] = p1.x; w3[t] = p1.y;
        }
    }
    const double bco = bcomb[bl];
    __syncthreads();

    for (int rr = 0; rr < 16; ++rr) {
        int r = wave * 16 + rr;
        const float* xr = x + (rowbase + r) * 256 + kc * 4;
        double a0 = 0.0, a1 = 0.0, a2 = 0.0, a3 = 0.0;
#pragma unroll
        for (int t = 0; t < 8; ++t) {
            float4 v = *(const float4*)(xr + t * 32);   // one 128B line/instr, 8x broadcast
            a0 += (double)v.x * w0[t];
            a1 += (double)v.y * w1[t];
            a2 += (double)v.z * w2[t];
            a3 += (double)v.w * w3[t];
        }
        double e = (a0 + a2) + (a1 + a3);
        e += __shfl_xor(e, 8);     // reduce over kc
        e += __shfl_xor(e, 16);
        e += __shfl_xor(e, 32);
        e += bco;
        int bid = bl;
#pragma unroll
        for (int d = 4; d; d >>= 1) {   // argmin over bl, first-index tie-break
            double o = __shfl_xor(e, d);
            int ob = __shfl_xor(bid, d);
            if (o < e || (o == e && ob < bid)) { e = o; bid = ob; }
        }
        if (lane == 0) bidl[r] = (unsigned char)bid;
    }
    __syncthreads();

    // block-level bucket, then one global atomic per non-empty branch
    if (tid < 64) {
        int b = bidl[tid];
        int p = atomicAdd(&cnt[b], 1);
        list[b][p] = (unsigned char)tid;
    }
    __syncthreads();
    if (tid < 8) base8[tid] = cnt[tid] ? atomicAdd(&gcnt[tid], cnt[tid]) : 0;
    __syncthreads();
#pragma unroll
    for (int j = tid; j < 512; j += 256) {
        int b = j >> 6, i = j & 63;
        if (i < cnt[b])
            perm[b * NROWS + base8[b] + i] = (int)rowbase + (int)list[b][i];
    }
}

// ---------- gemm: one (branch, 64-row tile) x 128 cols per block ----------
__global__ __launch_bounds__(256) void k_gemm(const float* __restrict__ x,
                                              const int* __restrict__ gcnt,
                                              const int* __restrict__ perm,
                                              const unsigned short* __restrict__ Wfold,
                                              const float* __restrict__ bfold,
                                              float* __restrict__ out) {
    __shared__ unsigned short xbf[64 * 264];
    __shared__ int rowid[64];
    int tid = threadIdx.x;

    // block -> (branch b, tile) from gcnt prefix over tile counts
    int t = blockIdx.x;
    int b = -1, tile = 0, m = 0;
    int accT = 0;
#pragma unroll
    for (int i = 0; i < 8; ++i) {
        int ci = gcnt[i];
        int Ti = (ci + 63) >> 6;
        if (b < 0 && t < accT + Ti) {
            b = i; tile = t - accT;
            int rem = ci - tile * 64;
            m = rem < 64 ? rem : 64;
        }
        accT += Ti;
    }
    if (b < 0) return;

    int pbase = b * NROWS + tile * 64;
    if (tid < 64) rowid[tid] = perm[pbase + (tid < m ? tid : 0)];
    __syncthreads();

    // stage 64 gathered rows -> bf16 LDS; 1KB contiguous per row slice
#pragma unroll 4
    for (int it = 0; it < 16; ++it) {
        int idx = it * 256 + tid;
        int r = idx >> 6, kq = idx & 63;
        float4 v = *(const float4*)(x + (size_t)rowid[r] * 256 + kq * 4);
        ushort4 pk4;
        pk4.x = f2bf(v.x); pk4.y = f2bf(v.y); pk4.z = f2bf(v.z); pk4.w = f2bf(v.w);
        *(ushort4*)&xbf[r * 264 + kq * 4] = pk4;
    }
    __syncthreads();

    int wave = tid >> 6, lane = tid & 63;
    int quad = lane >> 4, n16 = lane & 15;

    for (int cc = 0; cc < 2; ++cc) {
        int ct = wave + cc * 4;     // col tile 0..7
        const unsigned short* wp = Wfold + ((size_t)(b * 128 + ct * 16 + n16)) * 256 + quad * 8;
        bf16x8 Bf[8];
#pragma unroll
        for (int kt = 0; kt < 8; ++kt)
            Bf[kt] = __builtin_bit_cast(bf16x8, *(const u16x8*)(wp + kt * 32));
        float bias = bfold[b * 128 + ct * 16 + n16];

        for (int rg = 0; rg < 4; ++rg) {
            int s = rg * 16;
            const unsigned short* ap = &xbf[(s + n16) * 264 + quad * 8];
            bf16x8 Af[8];
#pragma unroll
            for (int kt = 0; kt < 8; ++kt)
                Af[kt] = __builtin_bit_cast(bf16x8, *(const u16x8*)(ap + kt * 32));

            f32x4 acc = {bias, bias, bias, bias};
#pragma unroll
            for (int kt = 0; kt < 8; ++kt)
                acc = __builtin_amdgcn_mfma_f32_16x16x32_bf16(Af[kt], Bf[kt], acc, 0, 0, 0);

#pragma unroll
            for (int reg = 0; reg < 4; ++reg) {
                int r16 = s + quad * 4 + reg;
                if (r16 < m)
                    out[(size_t)rowid[r16] * 128 + ct * 16 + n16] = acc[reg];
            }
        }
    }
}

extern "C" void kernel_launch(void* const* d_in, const int* in_sizes, int n_in,
                              void* d_out, int out_size, void* d_ws, size_t ws_size,
                              hipStream_t stream) {
    const float* x  = (const float*)d_in[0];
    const float* Wb = (const float*)d_in[1];
    const float* bb = (const float*)d_in[2];
    const float* Wc = (const float*)d_in[3];
    const float* bc = (const float*)d_in[4];
    const float* We = (const float*)d_in[5];
    const float* be = (const float*)d_in[6];
    float* out = (float*)d_out;

    unsigned char* ws = (unsigned char*)d_ws;
    double* Wcomb = (double*)ws;                               //       0 : 16384 B
    double* bcomb = (double*)(ws + 16384);                     //   16384 : 64 B
    unsigned short* Wfold = (unsigned short*)(ws + 16448);     //   16448 : 524288 B
    float* bfold = (float*)(ws + 540736);                      //  540736 : 4096 B
    int* gcnt = (int*)(ws + 544832);                           //  544832 : 64 B
    int* perm = (int*)(ws + 544896);                           //  544896 : 4194304 B (8 regions of N)

    hipLaunchKernelGGL(k_prep, dim3(144), dim3(256), 0, stream,
                       Wb, bb, Wc, bc, We, be, Wcomb, bcomb, Wfold, bfold, gcnt);
    hipLaunchKernelGGL(k_route, dim3(NROWS / 64), dim3(256), 0, stream,
                       x, Wcomb, bcomb, gcnt, perm);
    hipLaunchKernelGGL(k_gemm, dim3(NROWS / 64 + 7), dim3(256), 0, stream,
                       x, gcnt, perm, Wfold, bfold, out);
}

// Round 5
// 298.753 us; speedup vs baseline: 2.2734x; 1.2729x over previous
//
#include <hip/hip_runtime.h>

// BranchNet pipeline (3 kernels):
//   k_prep : Wcomb = Wb@We.T (fp64), bcomb; Wfold[b]=Wb@Wc[b] (bf16 [b][c][k]); bfold.
//   k_route: round-0 octet routing (lane=(row,branch), 8 rows/wave in parallel, LDS Wcomb)
//            + in-block compaction into per-branch regions perm[b*N+ofs]
//            + writes bf16 copy of x (xb) while rows are L1-hot.
//   k_gemm : per (branch, 64-row tile): gather xb rows -> LDS via global_load_lds
//            (XOR-swizzled source, linear LDS dest) -> 16x16x32 bf16 MFMA.
// Round-4 lesson: wave-per-row routing = dependent shfl chains + weight reload (VGPR=48),
// 157us. Round-3 lesson: never fuse routing VGPR pressure with MFMA phase.
// Sizes: N=131072, IN=256, HID=256, B=8, C=128.

#define NROWS 131072

typedef __bf16 bf16x8 __attribute__((ext_vector_type(8)));
typedef float  f32x4  __attribute__((ext_vector_type(4)));
typedef unsigned short u16x8 __attribute__((ext_vector_type(8)));

__device__ __forceinline__ unsigned short f2bf(float f) {
    unsigned u = __builtin_bit_cast(unsigned, f);
    u += 0x7fffu + ((u >> 16) & 1u);   // RNE
    return (unsigned short)(u >> 16);
}

__device__ __forceinline__ void glds16(const void* g, void* l) {
    __builtin_amdgcn_global_load_lds(
        (const __attribute__((address_space(1))) unsigned*)g,
        (__attribute__((address_space(3))) unsigned*)l, 16, 0, 0);
}

// ---------- prep: blocks 0..7 comb(b) [+zero gcnt], 8..15 bfold(b), 16..143 fold ----------
__global__ __launch_bounds__(256) void k_prep(const float* __restrict__ Wb,
                                              const float* __restrict__ bb,
                                              const float* __restrict__ Wc,
                                              const float* __restrict__ bc,
                                              const float* __restrict__ We,
                                              const float* __restrict__ be,
                                              double* __restrict__ Wcomb,
                                              double* __restrict__ bcomb,
                                              unsigned short* __restrict__ Wfold,
                                              float* __restrict__ bfold,
                                              int* __restrict__ gcnt) {
    __shared__ float clf[32][128];
    __shared__ float wbt[32][16];
    __shared__ double red[256];
    __shared__ float part[256];
    int blk = blockIdx.x, tid = threadIdx.x;

    if (blk < 8) {
        if (blk == 0 && tid < 16) gcnt[tid] = 0;
        int b = blk, k = tid;
        const float4* wbr = (const float4*)(Wb + k * 256);
        const float4* wer = (const float4*)(We + b * 256);
        double a0 = 0.0, a1 = 0.0, a2 = 0.0, a3 = 0.0;
#pragma unroll 8
        for (int j = 0; j < 64; ++j) {
            float4 u = wbr[j], w = wer[j];
            a0 += (double)u.x * (double)w.x;
            a1 += (double)u.y * (double)w.y;
            a2 += (double)u.z * (double)w.z;
            a3 += (double)u.w * (double)w.w;
        }
        Wcomb[b * 256 + k] = (a0 + a1) + (a2 + a3);

        red[k] = (double)bb[k] * (double)We[b * 256 + k];
        __syncthreads();
        for (int s = 128; s; s >>= 1) {
            if (k < s) red[k] += red[k + s];
            __syncthreads();
        }
        if (k == 0) bcomb[b] = red[0] + (double)be[b];
        return;
    }

    if (blk < 16) {
        int b = blk - 8;
        int c = tid & 127, hg = tid >> 7;
        float a = 0.f;
#pragma unroll 16
        for (int h = 0; h < 128; ++h)
            a += bb[hg * 128 + h] * Wc[((b * 256 + hg * 128 + h)) * 128 + c];
        part[tid] = a;
        __syncthreads();
        if (tid < 128) bfold[b * 128 + tid] = part[tid] + part[tid + 128] + bc[b * 128 + tid];
        return;
    }

    // fold: Wfold[b][c][k] bf16
    int idx0 = blk - 16;
    int kg = idx0 & 15, b = idx0 >> 4;
    int c = tid & 127, kh = tid >> 7;

    float acc[8];
#pragma unroll
    for (int j = 0; j < 8; ++j) acc[j] = 0.f;

    for (int ht = 0; ht < 8; ++ht) {
#pragma unroll
        for (int j = 0; j < 16; ++j) {
            int idx = tid + j * 256;
            int hh = idx >> 7, cc = idx & 127;
            clf[hh][cc] = Wc[(b * 256 + ht * 32 + hh) * 128 + cc];
        }
#pragma unroll
        for (int j = 0; j < 2; ++j) {
            int idx = tid + j * 256;
            int hh = idx & 31, kk = idx >> 5;
            wbt[hh][kk] = Wb[(kg * 16 + kk) * 256 + ht * 32 + hh];
        }
        __syncthreads();
        for (int h = 0; h < 32; ++h) {
            float wc = clf[h][c];
            float4 w0 = *(const float4*)&wbt[h][kh * 8];
            float4 w1 = *(const float4*)&wbt[h][kh * 8 + 4];
            acc[0] += w0.x * wc; acc[1] += w0.y * wc;
            acc[2] += w0.z * wc; acc[3] += w0.w * wc;
            acc[4] += w1.x * wc; acc[5] += w1.y * wc;
            acc[6] += w1.z * wc; acc[7] += w1.w * wc;
        }
        __syncthreads();
    }
    unsigned short o8[8];
#pragma unroll
    for (int j = 0; j < 8; ++j) o8[j] = f2bf(acc[j]);
    u16x8 pk;
#pragma unroll
    for (int j = 0; j < 8; ++j) pk[j] = o8[j];
    int base = (b * 128 + c) * 256 + kg * 16 + kh * 8;
    *(u16x8*)&Wfold[base] = pk;
}

// ---------- route: octet fp64 routing + xb write + fused compaction; 32 rows/block ----------
__global__ __launch_bounds__(256) void k_route(const float* __restrict__ x,
                                               const double* __restrict__ Wcomb,
                                               const double* __restrict__ bcomb,
                                               unsigned short* __restrict__ xb,
                                               int* __restrict__ gcnt,
                                               int* __restrict__ perm) {
    __shared__ double wc[8 * 258];   // stride 258 doubles -> conflict-free (round-0 verified)
    __shared__ double bco[8];
    __shared__ unsigned char bidl[32];
    __shared__ unsigned char list[8][32];
    __shared__ int cnt[8], base8[8];
    int tid = threadIdx.x;
    const size_t rowbase = (size_t)blockIdx.x * 32;

    for (int j = tid; j < 2048; j += 256) {
        int b = j >> 8, k = j & 255;
        wc[b * 258 + k] = Wcomb[j];
    }
    if (tid < 8) { bco[tid] = bcomb[tid]; cnt[tid] = 0; }

    // bf16 copy of this block's rows (RNE f2bf, logical layout; L1-warms x for routing)
#pragma unroll
    for (int it = 0; it < 4; ++it) {
        int idx = it * 256 + tid;        // 1024 chunks of 8 bf16
        int r = idx >> 5, c = idx & 31;
        const float* xp = x + (rowbase + r) * 256 + c * 8;
        float4 f0 = *(const float4*)xp;
        float4 f1 = *(const float4*)(xp + 4);
        u16x8 pk;
        pk[0] = f2bf(f0.x); pk[1] = f2bf(f0.y); pk[2] = f2bf(f0.z); pk[3] = f2bf(f0.w);
        pk[4] = f2bf(f1.x); pk[5] = f2bf(f1.y); pk[6] = f2bf(f1.z); pk[7] = f2bf(f1.w);
        *(u16x8*)&xb[(rowbase + r) * 256 + c * 8] = pk;
    }
    __syncthreads();

    // routing: lane=(row oct, branch b); 8 rows per wave in parallel (round-0 verified math)
    int b = tid & 7, oct = tid >> 3;
    int row = blockIdx.x * 32 + oct;
    const float* xr = x + (size_t)row * 256;
    const double* wcr = wc + b * 258;
    double a0 = bco[b], a1 = 0.0, a2 = 0.0, a3 = 0.0;
    for (int k = 0; k < 256; k += 8) {
        float4 xv0 = *(const float4*)(xr + k);
        float4 xv1 = *(const float4*)(xr + k + 4);
        double2 w0 = *(const double2*)(wcr + k);
        double2 w1 = *(const double2*)(wcr + k + 2);
        double2 w2 = *(const double2*)(wcr + k + 4);
        double2 w3 = *(const double2*)(wcr + k + 6);
        a0 += (double)xv0.x * w0.x; a1 += (double)xv0.y * w0.y;
        a2 += (double)xv0.z * w1.x; a3 += (double)xv0.w * w1.y;
        a0 += (double)xv1.x * w2.x; a1 += (double)xv1.y * w2.y;
        a2 += (double)xv1.z * w3.x; a3 += (double)xv1.w * w3.y;
    }
    double best = (a0 + a2) + (a1 + a3);
    int bbx = b;
    for (int d = 4; d; d >>= 1) {
        double o  = __shfl_down(best, (unsigned)d, 8);
        int    ob = __shfl_down(bbx,  (unsigned)d, 8);
        if (o < best || (o == best && ob < bbx)) { best = o; bbx = ob; }
    }
    if (b == 0) bidl[oct] = (unsigned char)bbx;
    __syncthreads();

    // in-block bucket + per-branch global regions (round-4 verified)
    if (tid < 32) {
        int bb = bidl[tid];
        int p = atomicAdd(&cnt[bb], 1);
        list[bb][p] = (unsigned char)tid;
    }
    __syncthreads();
    if (tid < 8) base8[tid] = cnt[tid] ? atomicAdd(&gcnt[tid], cnt[tid]) : 0;
    __syncthreads();
    {
        int bb = tid >> 5, i = tid & 31;
        if (i < cnt[bb])
            perm[bb * NROWS + base8[bb] + i] = (int)rowbase + (int)list[bb][i];
    }
}

// ---------- gemm: one (branch, 64-row tile) x 128 cols; glds-staged bf16 rows ----------
__global__ __launch_bounds__(256) void k_gemm(const unsigned short* __restrict__ xb,
                                              const int* __restrict__ gcnt,
                                              const int* __restrict__ perm,
                                              const unsigned short* __restrict__ Wfold,
                                              const float* __restrict__ bfold,
                                              float* __restrict__ out) {
    __shared__ unsigned short xbf[64 * 256];   // 32 KB, linear (glds dest must be linear)
    __shared__ int rowid[64];
    int tid = threadIdx.x;

    // block -> (branch b, tile) from gcnt prefix over tile counts
    int t = blockIdx.x;
    int b = -1, tile = 0, m = 0;
    int accT = 0;
#pragma unroll
    for (int i = 0; i < 8; ++i) {
        int ci = gcnt[i];
        int Ti = (ci + 63) >> 6;
        if (b < 0 && t < accT + Ti) {
            b = i; tile = t - accT;
            int rem = ci - tile * 64;
            m = rem < 64 ? rem : 64;
        }
        accT += Ti;
    }
    if (b < 0) return;

    int pbase = b * NROWS + tile * 64;
    if (tid < 64) rowid[tid] = perm[pbase + (tid < m ? tid : 0)];
    __syncthreads();

    int wave = tid >> 6, lane = tid & 63;

    // stage: 8 global_load_lds_dwordx4 per wave. LDS dest linear (base + lane*16);
    // source chunk XOR-swizzled by (ldsrow&7) so the Af ds_read_b128 below is
    // bank-quad-uniform (rule #21: swizzle source + read, keep LDS linear).
#pragma unroll
    for (int it = 0; it < 8; ++it) {
        int ci = it * 256 + tid;            // chunk id 0..2047 (16B chunks)
        int r = ci >> 5, j = ci & 31;       // lds row, chunk-in-row
        const unsigned short* src = xb + (size_t)rowid[r] * 256 + (size_t)((j ^ (r & 7)) * 8);
        unsigned short* dst = xbf + (size_t)(it * 256 + wave * 64) * 8;  // wave-uniform
        glds16(src, dst);
    }
    __syncthreads();

    int quad = lane >> 4, n16 = lane & 15;
    const int h = n16 & 7;   // swizzle key = lds row & 7

    for (int cc = 0; cc < 2; ++cc) {
        int ct = wave + cc * 4;     // col tile 0..7
        const unsigned short* wp = Wfold + ((size_t)(b * 128 + ct * 16 + n16)) * 256 + quad * 8;
        bf16x8 Bf[8];
#pragma unroll
        for (int kt = 0; kt < 8; ++kt)
            Bf[kt] = __builtin_bit_cast(bf16x8, *(const u16x8*)(wp + kt * 32));
        float bias = bfold[b * 128 + ct * 16 + n16];

        for (int rg = 0; rg < 4; ++rg) {
            int s = rg * 16;
            const unsigned short* rowp = &xbf[(s + n16) * 256];
            bf16x8 Af[8];
#pragma unroll
            for (int kt = 0; kt < 8; ++kt)
                Af[kt] = __builtin_bit_cast(bf16x8,
                         *(const u16x8*)(rowp + ((kt * 4 + quad) ^ h) * 8));

            f32x4 acc = {bias, bias, bias, bias};
#pragma unroll
            for (int kt = 0; kt < 8; ++kt)
                acc = __builtin_amdgcn_mfma_f32_16x16x32_bf16(Af[kt], Bf[kt], acc, 0, 0, 0);

#pragma unroll
            for (int reg = 0; reg < 4; ++reg) {
                int r16 = s + quad * 4 + reg;
                if (r16 < m)
                    out[(size_t)rowid[r16] * 128 + ct * 16 + n16] = acc[reg];
            }
        }
    }
}

extern "C" void kernel_launch(void* const* d_in, const int* in_sizes, int n_in,
                              void* d_out, int out_size, void* d_ws, size_t ws_size,
                              hipStream_t stream) {
    const float* x  = (const float*)d_in[0];
    const float* Wb = (const float*)d_in[1];
    const float* bb = (const float*)d_in[2];
    const float* Wc = (const float*)d_in[3];
    const float* bc = (const float*)d_in[4];
    const float* We = (const float*)d_in[5];
    const float* be = (const float*)d_in[6];
    float* out = (float*)d_out;

    unsigned char* ws = (unsigned char*)d_ws;
    double* Wcomb = (double*)ws;                               //       0 : 16384 B
    double* bcomb = (double*)(ws + 16384);                     //   16384 : 64 B
    unsigned short* Wfold = (unsigned short*)(ws + 16448);     //   16448 : 524288 B
    float* bfold = (float*)(ws + 540736);                      //  540736 : 4096 B
    int* gcnt = (int*)(ws + 544832);                           //  544832 : 64 B
    int* perm = (int*)(ws + 544896);                           //  544896 : 4194304 B
    unsigned short* xb = (unsigned short*)(ws + 4739200);      // 4739200 : 67108864 B (bf16 x)

    hipLaunchKernelGGL(k_prep, dim3(144), dim3(256), 0, stream,
                       Wb, bb, Wc, bc, We, be, Wcomb, bcomb, Wfold, bfold, gcnt);
    hipLaunchKernelGGL(k_route, dim3(NROWS / 32), dim3(256), 0, stream,
                       x, Wcomb, bcomb, xb, gcnt, perm);
    hipLaunchKernelGGL(k_gemm, dim3(NROWS / 64 + 7), dim3(256), 0, stream,
                       xb, gcnt, perm, Wfold, bfold, out);
}